// Round 1
// baseline (1446.479 us; speedup 1.0000x reference)
//
#include <hip/hip_runtime.h>
#include <cstddef>

#define T_SEQ 2048
#define BATCH 4
#define DMODEL 512
#define DINNER 1024
#define NSTATE 16

__device__ __forceinline__ float silu_f(float v) { return v / (1.f + __expf(-v)); }
__device__ __forceinline__ float softplus_f(float v) { return v > 20.f ? v : log1pf(__expf(v)); }

// ---------------------------------------------------------------------------
// Generic tiled fp32 GEMM: C[m,n] = sum_k A[m*K+k] * Bw[n*K+k]
// BM=BN=64, BK=16, 256 threads, 4x4 micro-tile per thread.
// MODE 0: plain store to C0 (stride N)
// MODE 1: in_proj split: n<1024 -> C0[m*1024+n] (xs_raw); n>=1024 -> C1[m*1024+n-1024] = silu(v)
// MODE 2: dt: v += bias[n]; softplus; C0[m*1024+n]
// ---------------------------------------------------------------------------
template <int MODE>
__global__ __launch_bounds__(256) void gemm64(
    const float* __restrict__ A, const float* __restrict__ Bw,
    float* __restrict__ C0, float* __restrict__ C1,
    const float* __restrict__ bias, int M, int N, int K)
{
    __shared__ float As[16][68];
    __shared__ float Bs[16][68];
    const int tid = threadIdx.x;
    const int m0 = blockIdx.y * 64;
    const int n0 = blockIdx.x * 64;
    const int kk = tid & 15;   // k within tile
    const int r  = tid >> 4;   // 0..15
    float acc[4][4] = {};

    for (int kt = 0; kt < K; kt += 16) {
        #pragma unroll
        for (int i = 0; i < 4; ++i)
            As[kk][r + 16 * i] = A[(size_t)(m0 + r + 16 * i) * K + kt + kk];
        #pragma unroll
        for (int i = 0; i < 4; ++i)
            Bs[kk][r + 16 * i] = Bw[(size_t)(n0 + r + 16 * i) * K + kt + kk];
        __syncthreads();

        const int ty = tid >> 4, tx = tid & 15;
        #pragma unroll
        for (int k2 = 0; k2 < 16; ++k2) {
            float av[4], bv[4];
            #pragma unroll
            for (int i = 0; i < 4; ++i) av[i] = As[k2][ty * 4 + i];
            #pragma unroll
            for (int j = 0; j < 4; ++j) bv[j] = Bs[k2][tx * 4 + j];
            #pragma unroll
            for (int i = 0; i < 4; ++i)
                #pragma unroll
                for (int j = 0; j < 4; ++j)
                    acc[i][j] = fmaf(av[i], bv[j], acc[i][j]);
        }
        __syncthreads();
    }

    const int ty = tid >> 4, tx = tid & 15;
    #pragma unroll
    for (int i = 0; i < 4; ++i) {
        const int m = m0 + ty * 4 + i;
        #pragma unroll
        for (int j = 0; j < 4; ++j) {
            const int n = n0 + tx * 4 + j;
            float v = acc[i][j];
            if (MODE == 0) {
                C0[(size_t)m * N + n] = v;
            } else if (MODE == 1) {
                if (n < DINNER) C0[(size_t)m * DINNER + n] = v;
                else            C1[(size_t)m * DINNER + (n - DINNER)] = silu_f(v);
            } else { // MODE 2
                v += bias[n];
                C0[(size_t)m * DINNER + n] = softplus_f(v);
            }
        }
    }
}

// ---------------------------------------------------------------------------
// Causal depthwise conv (width 4) + bias + silu.
// xs[b,t,d] = silu(conv_b[d] + sum_k xs_raw[b,t-3+k,d] * w[d,k])
// ---------------------------------------------------------------------------
__global__ __launch_bounds__(256) void conv_silu_kernel(
    const float* __restrict__ xs_raw, const float* __restrict__ w,
    const float* __restrict__ bconv, float* __restrict__ xs)
{
    const size_t idx = (size_t)blockIdx.x * 256 + threadIdx.x; // over B*T*DINNER
    const int d = (int)(idx & (DINNER - 1));
    const int bt = (int)(idx >> 10);
    const int t = bt & (T_SEQ - 1);
    float acc = bconv[d];
    #pragma unroll
    for (int k = 0; k < 4; ++k) {
        const int tt = t + k - 3;
        if (tt >= 0)
            acc = fmaf(xs_raw[(size_t)(bt + k - 3) * DINNER + d], w[d * 4 + k], acc);
    }
    xs[idx] = silu_f(acc);
}

// ---------------------------------------------------------------------------
// B/C projections: one block per (b,t) row. Bm[bt,n] = sum_d xs[bt,d]*bw[n,d]
// ---------------------------------------------------------------------------
__global__ __launch_bounds__(256) void bc_proj_kernel(
    const float* __restrict__ xs, const float* __restrict__ bw,
    const float* __restrict__ cw, float* __restrict__ Bm, float* __restrict__ Cm)
{
    __shared__ float row[DINNER];
    const int bt = blockIdx.x;
    const int tid = threadIdx.x;
    const float* xr = xs + (size_t)bt * DINNER;
    for (int i = tid; i < DINNER; i += 256) row[i] = xr[i];
    __syncthreads();

    const int o = tid >> 3;     // 0..31
    const int part = tid & 7;   // 0..7
    const float* w = (o < NSTATE) ? (bw + (size_t)o * DINNER)
                                  : (cw + (size_t)(o - NSTATE) * DINNER);
    float s = 0.f;
    for (int k = part; k < DINNER; k += 8)
        s = fmaf(row[k], w[k], s);
    s += __shfl_xor(s, 1);
    s += __shfl_xor(s, 2);
    s += __shfl_xor(s, 4);
    if (part == 0) {
        if (o < NSTATE) Bm[(size_t)bt * NSTATE + o] = s;
        else            Cm[(size_t)bt * NSTATE + (o - NSTATE)] = s;
    }
}

// ---------------------------------------------------------------------------
// Selective scan. Thread layout: n = tid&15, d = blockIdx.x*16 + (tid>>4),
// b = blockIdx.y. h kept in a register, reduced over n by shfl_xor.
// Fused epilogue: y = (scan + xs*D) * silu(res), stored to yfin.
// ---------------------------------------------------------------------------
__global__ __launch_bounds__(256) void scan_kernel(
    const float* __restrict__ delta, const float* __restrict__ xs,
    const float* __restrict__ Bm, const float* __restrict__ Cm,
    const float* __restrict__ A_log, const float* __restrict__ Dp,
    const float* __restrict__ silures, float* __restrict__ yfin)
{
    const int tid = threadIdx.x;
    const int n = tid & 15;
    const int dl = tid >> 4;
    const int d = blockIdx.x * 16 + dl;
    const int b = blockIdx.y;

    const float a = -__expf(A_log[d * NSTATE + n]);
    const float Dd = Dp[d];
    float h = 0.f;
    const size_t base = (size_t)b * T_SEQ;

    // prefetch t = 0
    size_t idx0 = base * DINNER + d;
    float dlt = delta[idx0], xv = xs[idx0], sr = silures[idx0];
    float Bv = Bm[base * NSTATE + n], Cv = Cm[base * NSTATE + n];

    for (int t = 0; t < T_SEQ; ++t) {
        float dlt_n = 0.f, xv_n = 0.f, sr_n = 0.f, Bv_n = 0.f, Cv_n = 0.f;
        if (t < T_SEQ - 1) {
            const size_t idx = (base + t + 1) * DINNER + d;
            dlt_n = delta[idx]; xv_n = xs[idx]; sr_n = silures[idx];
            Bv_n = Bm[(base + t + 1) * NSTATE + n];
            Cv_n = Cm[(base + t + 1) * NSTATE + n];
        }
        const float dA = __expf(dlt * a);
        h = fmaf(dA, h, dlt * Bv * xv);
        float p = h * Cv;
        p += __shfl_xor(p, 1);
        p += __shfl_xor(p, 2);
        p += __shfl_xor(p, 4);
        p += __shfl_xor(p, 8);
        if (n == 0) {
            const float y = fmaf(xv, Dd, p);
            yfin[(base + t) * DINNER + d] = y * sr;
        }
        dlt = dlt_n; xv = xv_n; sr = sr_n; Bv = Bv_n; Cv = Cv_n;
    }
}

// ---------------------------------------------------------------------------
extern "C" void kernel_launch(void* const* d_in, const int* in_sizes, int n_in,
                              void* d_out, int out_size, void* d_ws, size_t ws_size,
                              hipStream_t stream)
{
    const float* x          = (const float*)d_in[0];
    const float* in_proj_w  = (const float*)d_in[1];
    const float* conv_w     = (const float*)d_in[2];
    const float* conv_b     = (const float*)d_in[3];
    const float* b_proj_w   = (const float*)d_in[4];
    const float* c_proj_w   = (const float*)d_in[5];
    const float* dt_proj_w  = (const float*)d_in[6];
    const float* dt_proj_b  = (const float*)d_in[7];
    const float* A_log      = (const float*)d_in[8];
    const float* Dp         = (const float*)d_in[9];
    const float* out_proj_w = (const float*)d_in[10];
    float* out = (float*)d_out;

    const size_t BT = (size_t)BATCH * T_SEQ;            // 8192
    const size_t SZ = BT * DINNER;                      // 8388608 floats

    float* ws       = (float*)d_ws;
    float* xs_raw   = ws;                // [BT, DINNER] (reused as yfin later)
    float* xs       = ws + SZ;           // [BT, DINNER]
    float* silures  = ws + 2 * SZ;       // [BT, DINNER]
    float* delta    = ws + 3 * SZ;       // [BT, DINNER]
    float* Bm       = ws + 4 * SZ;       // [BT, NSTATE]
    float* Cm       = Bm + BT * NSTATE;  // [BT, NSTATE]
    float* yfin     = xs_raw;            // reuse (dead after conv)

    // 1. in_proj: xr = x @ in_proj_w^T -> xs_raw | silu(res)
    gemm64<1><<<dim3(2 * DINNER / 64, BT / 64), 256, 0, stream>>>(
        x, in_proj_w, xs_raw, silures, nullptr, (int)BT, 2 * DINNER, DMODEL);

    // 2. conv + bias + silu
    conv_silu_kernel<<<dim3(SZ / 256), 256, 0, stream>>>(xs_raw, conv_w, conv_b, xs);

    // 3. delta = softplus(xs @ dt_proj_w^T + b)
    gemm64<2><<<dim3(DINNER / 64, BT / 64), 256, 0, stream>>>(
        xs, dt_proj_w, delta, nullptr, dt_proj_b, (int)BT, DINNER, DINNER);

    // 4. B/C projections
    bc_proj_kernel<<<dim3((unsigned)BT), 256, 0, stream>>>(xs, b_proj_w, c_proj_w, Bm, Cm);

    // 5. selective scan (fused +xs*D and *silu(res))
    scan_kernel<<<dim3(DINNER / 16, BATCH), 256, 0, stream>>>(
        delta, xs, Bm, Cm, A_log, Dp, silures, yfin);

    // 6. out_proj
    gemm64<0><<<dim3(DMODEL / 64, BT / 64), 256, 0, stream>>>(
        yfin, out_proj_w, out, nullptr, nullptr, (int)BT, DMODEL, DINNER);
}

// Round 2
// 983.724 us; speedup vs baseline: 1.4704x; 1.4704x over previous
//
#include <hip/hip_runtime.h>
#include <cstddef>

#define T_SEQ 2048
#define BATCH 4
#define DMODEL 512
#define DINNER 1024
#define NSTATE 16
#define NCHUNK 64
#define CLEN   32   // T_SEQ / NCHUNK

__device__ __forceinline__ float silu_f(float v) { return v / (1.f + __expf(-v)); }
__device__ __forceinline__ float softplus_f(float v) { return v > 20.f ? v : log1pf(__expf(v)); }

// ---------------------------------------------------------------------------
// Generic tiled fp32 GEMM: C[m,n] = sum_k A[m*K+k] * Bw[n*K+k]
// BM=BN=64, BK=16, 256 threads, 4x4 micro-tile per thread.
// MODE 0: plain store to C0 (stride N)
// MODE 1: in_proj split: n<1024 -> C0 (xs_raw); n>=1024 -> C1 = silu(v)
// MODE 2: dt: v += bias[n]; softplus; C0
// ---------------------------------------------------------------------------
template <int MODE>
__global__ __launch_bounds__(256) void gemm64(
    const float* __restrict__ A, const float* __restrict__ Bw,
    float* __restrict__ C0, float* __restrict__ C1,
    const float* __restrict__ bias, int M, int N, int K)
{
    __shared__ float As[16][68];
    __shared__ float Bs[16][68];
    const int tid = threadIdx.x;
    const int m0 = blockIdx.y * 64;
    const int n0 = blockIdx.x * 64;
    const int kk = tid & 15;
    const int r  = tid >> 4;
    float acc[4][4] = {};

    for (int kt = 0; kt < K; kt += 16) {
        #pragma unroll
        for (int i = 0; i < 4; ++i)
            As[kk][r + 16 * i] = A[(size_t)(m0 + r + 16 * i) * K + kt + kk];
        #pragma unroll
        for (int i = 0; i < 4; ++i)
            Bs[kk][r + 16 * i] = Bw[(size_t)(n0 + r + 16 * i) * K + kt + kk];
        __syncthreads();

        const int ty = tid >> 4, tx = tid & 15;
        #pragma unroll
        for (int k2 = 0; k2 < 16; ++k2) {
            float av[4], bv[4];
            #pragma unroll
            for (int i = 0; i < 4; ++i) av[i] = As[k2][ty * 4 + i];
            #pragma unroll
            for (int j = 0; j < 4; ++j) bv[j] = Bs[k2][tx * 4 + j];
            #pragma unroll
            for (int i = 0; i < 4; ++i)
                #pragma unroll
                for (int j = 0; j < 4; ++j)
                    acc[i][j] = fmaf(av[i], bv[j], acc[i][j]);
        }
        __syncthreads();
    }

    const int ty = tid >> 4, tx = tid & 15;
    #pragma unroll
    for (int i = 0; i < 4; ++i) {
        const int m = m0 + ty * 4 + i;
        #pragma unroll
        for (int j = 0; j < 4; ++j) {
            const int n = n0 + tx * 4 + j;
            float v = acc[i][j];
            if (MODE == 0) {
                C0[(size_t)m * N + n] = v;
            } else if (MODE == 1) {
                if (n < DINNER) C0[(size_t)m * DINNER + n] = v;
                else            C1[(size_t)m * DINNER + (n - DINNER)] = silu_f(v);
            } else {
                v += bias[n];
                C0[(size_t)m * DINNER + n] = softplus_f(v);
            }
        }
    }
}

// ---------------------------------------------------------------------------
// Causal depthwise conv (width 4) + bias + silu.
// ---------------------------------------------------------------------------
__global__ __launch_bounds__(256) void conv_silu_kernel(
    const float* __restrict__ xs_raw, const float* __restrict__ w,
    const float* __restrict__ bconv, float* __restrict__ xs)
{
    const size_t idx = (size_t)blockIdx.x * 256 + threadIdx.x;
    const int d = (int)(idx & (DINNER - 1));
    const int bt = (int)(idx >> 10);
    const int t = bt & (T_SEQ - 1);
    float acc = bconv[d];
    #pragma unroll
    for (int k = 0; k < 4; ++k) {
        const int tt = t + k - 3;
        if (tt >= 0)
            acc = fmaf(xs_raw[(size_t)(bt + k - 3) * DINNER + d], w[d * 4 + k], acc);
    }
    xs[idx] = silu_f(acc);
}

// ---------------------------------------------------------------------------
// B/C projections: one block per (b,t) row.
// ---------------------------------------------------------------------------
__global__ __launch_bounds__(256) void bc_proj_kernel(
    const float* __restrict__ xs, const float* __restrict__ bw,
    const float* __restrict__ cw, float* __restrict__ Bm, float* __restrict__ Cm)
{
    __shared__ float row[DINNER];
    const int bt = blockIdx.x;
    const int tid = threadIdx.x;
    const float* xr = xs + (size_t)bt * DINNER;
    for (int i = tid; i < DINNER; i += 256) row[i] = xr[i];
    __syncthreads();

    const int o = tid >> 3;
    const int part = tid & 7;
    const float* w = (o < NSTATE) ? (bw + (size_t)o * DINNER)
                                  : (cw + (size_t)(o - NSTATE) * DINNER);
    float s = 0.f;
    for (int k = part; k < DINNER; k += 8)
        s = fmaf(row[k], w[k], s);
    s += __shfl_xor(s, 1);
    s += __shfl_xor(s, 2);
    s += __shfl_xor(s, 4);
    if (part == 0) {
        if (o < NSTATE) Bm[(size_t)bt * NSTATE + o] = s;
        else            Cm[(size_t)bt * NSTATE + (o - NSTATE)] = s;
    }
}

// ---------------------------------------------------------------------------
// Chunked scan, phase 1: per (b, d, chunk) thread, all 16 states in registers.
// Computes P[n] = prod_t dA, S[n] = chunk-local state (h0 = 0).
// ---------------------------------------------------------------------------
__global__ __launch_bounds__(256) void scan_phase1(
    const float* __restrict__ delta, const float* __restrict__ xs,
    const float* __restrict__ Bm, const float* __restrict__ A_log,
    float* __restrict__ Pbuf, float* __restrict__ Sbuf)
{
    const int tid = threadIdx.x;
    const int d = blockIdx.x * 256 + tid;
    const int c = blockIdx.y;
    const int b = blockIdx.z;

    float a[16], h[16], P[16];
    #pragma unroll
    for (int q = 0; q < 4; ++q)
        *(float4*)(a + 4 * q) = ((const float4*)(A_log + (size_t)d * NSTATE))[q];
    #pragma unroll
    for (int n = 0; n < 16; ++n) { a[n] = -__expf(a[n]); h[n] = 0.f; P[n] = 1.f; }

    const size_t base = (size_t)b * T_SEQ + (size_t)c * CLEN;
    for (int i = 0; i < CLEN; ++i) {
        const size_t bt = base + i;
        const float dlt = delta[bt * DINNER + d];
        const float xv  = xs[bt * DINNER + d];
        float Bn[16];
        #pragma unroll
        for (int q = 0; q < 4; ++q)
            *(float4*)(Bn + 4 * q) = ((const float4*)(Bm + bt * NSTATE))[q];
        const float tmp = dlt * xv;
        #pragma unroll
        for (int n = 0; n < 16; ++n) {
            const float dA = __expf(dlt * a[n]);
            P[n] *= dA;
            h[n] = fmaf(dA, h[n], tmp * Bn[n]);
        }
    }

    float* pp = Pbuf + ((((size_t)b * NCHUNK + c) * DINNER + d) * NSTATE);
    float* sp = Sbuf + ((((size_t)b * NCHUNK + c) * DINNER + d) * NSTATE);
    #pragma unroll
    for (int q = 0; q < 4; ++q) {
        ((float4*)pp)[q] = *(float4*)(P + 4 * q);
        ((float4*)sp)[q] = *(float4*)(h + 4 * q);
    }
}

// ---------------------------------------------------------------------------
// Phase 2: serial combine across chunks per (b,d,n). Writes chunk-entry state.
// ---------------------------------------------------------------------------
__global__ __launch_bounds__(256) void scan_phase2(
    const float* __restrict__ Pbuf, const float* __restrict__ Sbuf,
    float* __restrict__ Hbuf)
{
    const size_t g = (size_t)blockIdx.x * 256 + threadIdx.x; // over B*DINNER*NSTATE
    const size_t b = g / (DINNER * NSTATE);
    const size_t r = g - b * (DINNER * NSTATE);
    float h = 0.f;
    #pragma unroll 4
    for (int c = 0; c < NCHUNK; ++c) {
        const size_t off = ((size_t)(b * NCHUNK + c)) * (DINNER * NSTATE) + r;
        Hbuf[off] = h;
        h = fmaf(Pbuf[off], h, Sbuf[off]);
    }
}

// ---------------------------------------------------------------------------
// Phase 3: replay chunk from its entry state; fused y = (h·C + xs*D)*silu(res).
// ---------------------------------------------------------------------------
__global__ __launch_bounds__(256) void scan_phase3(
    const float* __restrict__ delta, const float* __restrict__ xs,
    const float* __restrict__ Bm, const float* __restrict__ Cm,
    const float* __restrict__ A_log, const float* __restrict__ Dp,
    const float* __restrict__ silures, const float* __restrict__ Hbuf,
    float* __restrict__ yfin)
{
    const int tid = threadIdx.x;
    const int d = blockIdx.x * 256 + tid;
    const int c = blockIdx.y;
    const int b = blockIdx.z;

    float a[16], h[16];
    #pragma unroll
    for (int q = 0; q < 4; ++q)
        *(float4*)(a + 4 * q) = ((const float4*)(A_log + (size_t)d * NSTATE))[q];
    #pragma unroll
    for (int n = 0; n < 16; ++n) a[n] = -__expf(a[n]);

    const float* hp = Hbuf + ((((size_t)b * NCHUNK + c) * DINNER + d) * NSTATE);
    #pragma unroll
    for (int q = 0; q < 4; ++q)
        *(float4*)(h + 4 * q) = ((const float4*)hp)[q];

    const float Dd = Dp[d];
    const size_t base = (size_t)b * T_SEQ + (size_t)c * CLEN;
    for (int i = 0; i < CLEN; ++i) {
        const size_t bt = base + i;
        const float dlt = delta[bt * DINNER + d];
        const float xv  = xs[bt * DINNER + d];
        const float sr  = silures[bt * DINNER + d];
        float Bn[16], Cn[16];
        #pragma unroll
        for (int q = 0; q < 4; ++q) {
            *(float4*)(Bn + 4 * q) = ((const float4*)(Bm + bt * NSTATE))[q];
            *(float4*)(Cn + 4 * q) = ((const float4*)(Cm + bt * NSTATE))[q];
        }
        const float tmp = dlt * xv;
        float p = 0.f;
        #pragma unroll
        for (int n = 0; n < 16; ++n) {
            const float dA = __expf(dlt * a[n]);
            h[n] = fmaf(dA, h[n], tmp * Bn[n]);
            p = fmaf(h[n], Cn[n], p);
        }
        const float y = fmaf(xv, Dd, p);
        yfin[bt * DINNER + d] = y * sr;
    }
}

// ---------------------------------------------------------------------------
extern "C" void kernel_launch(void* const* d_in, const int* in_sizes, int n_in,
                              void* d_out, int out_size, void* d_ws, size_t ws_size,
                              hipStream_t stream)
{
    const float* x          = (const float*)d_in[0];
    const float* in_proj_w  = (const float*)d_in[1];
    const float* conv_w     = (const float*)d_in[2];
    const float* conv_b     = (const float*)d_in[3];
    const float* b_proj_w   = (const float*)d_in[4];
    const float* c_proj_w   = (const float*)d_in[5];
    const float* dt_proj_w  = (const float*)d_in[6];
    const float* dt_proj_b  = (const float*)d_in[7];
    const float* A_log      = (const float*)d_in[8];
    const float* Dp         = (const float*)d_in[9];
    const float* out_proj_w = (const float*)d_in[10];
    float* out = (float*)d_out;

    const size_t BT = (size_t)BATCH * T_SEQ;   // 8192
    const size_t SZ = BT * DINNER;             // 8388608 floats (32 MB)
    const size_t PS = (size_t)BATCH * NCHUNK * DINNER * NSTATE; // 4194304 floats (16 MB)

    float* ws       = (float*)d_ws;
    float* xs_raw   = ws;                 // [BT, DINNER]; later: P | S; later: yfin
    float* xs       = ws + SZ;
    float* silures  = ws + 2 * SZ;
    float* delta    = ws + 3 * SZ;
    float* Bm       = ws + 4 * SZ;        // [BT, NSTATE]
    float* Cm       = Bm + BT * NSTATE;
    float* Hbuf     = Cm + BT * NSTATE;   // [B, NC, DINNER, NSTATE] 16 MB
    float* Pbuf     = xs_raw;             // aliases xs_raw (dead after conv)
    float* Sbuf     = xs_raw + PS;
    float* yfin     = xs_raw;             // aliases P/S (dead after phase2)

    // 1. in_proj
    gemm64<1><<<dim3(2 * DINNER / 64, BT / 64), 256, 0, stream>>>(
        x, in_proj_w, xs_raw, silures, nullptr, (int)BT, 2 * DINNER, DMODEL);

    // 2. conv + bias + silu
    conv_silu_kernel<<<dim3((unsigned)(SZ / 256)), 256, 0, stream>>>(xs_raw, conv_w, conv_b, xs);

    // 3. delta = softplus(xs @ dt_proj_w^T + b)
    gemm64<2><<<dim3(DINNER / 64, BT / 64), 256, 0, stream>>>(
        xs, dt_proj_w, delta, nullptr, dt_proj_b, (int)BT, DINNER, DINNER);

    // 4. B/C projections
    bc_proj_kernel<<<dim3((unsigned)BT), 256, 0, stream>>>(xs, b_proj_w, c_proj_w, Bm, Cm);

    // 5. chunked selective scan
    scan_phase1<<<dim3(DINNER / 256, NCHUNK, BATCH), 256, 0, stream>>>(
        delta, xs, Bm, A_log, Pbuf, Sbuf);
    scan_phase2<<<dim3((unsigned)((BATCH * DINNER * NSTATE) / 256)), 256, 0, stream>>>(
        Pbuf, Sbuf, Hbuf);
    scan_phase3<<<dim3(DINNER / 256, NCHUNK, BATCH), 256, 0, stream>>>(
        delta, xs, Bm, Cm, A_log, Dp, silures, Hbuf, yfin);

    // 6. out_proj
    gemm64<0><<<dim3(DMODEL / 64, BT / 64), 256, 0, stream>>>(
        yfin, out_proj_w, out, nullptr, nullptr, (int)BT, DMODEL, DINNER);
}

// Round 3
// 448.834 us; speedup vs baseline: 3.2228x; 2.1917x over previous
//
#include <hip/hip_runtime.h>
#include <hip/hip_bf16.h>
#include <cstddef>

#define T_SEQ 2048
#define BATCH 4
#define DMODEL 512
#define DINNER 1024
#define NSTATE 16
#define NCHUNK 64
#define CLEN   32   // T_SEQ / NCHUNK

typedef __attribute__((ext_vector_type(8))) short bf16x8;   // MFMA A/B operand
typedef __attribute__((ext_vector_type(4))) float f32x4;    // MFMA C/D
typedef __attribute__((ext_vector_type(8))) unsigned short u16x8;

__device__ __forceinline__ float silu_f(float v) { return v / (1.f + __expf(-v)); }
__device__ __forceinline__ float softplus_f(float v) { return v > 20.f ? v : log1pf(__expf(v)); }

__device__ __forceinline__ u16x8 cvt8_bf16(const float4 a, const float4 b) {
    union { __hip_bfloat162 h; unsigned int u; } c0, c1, c2, c3;
    c0.h = __float22bfloat162_rn(make_float2(a.x, a.y));
    c1.h = __float22bfloat162_rn(make_float2(a.z, a.w));
    c2.h = __float22bfloat162_rn(make_float2(b.x, b.y));
    c3.h = __float22bfloat162_rn(make_float2(b.z, b.w));
    union { u16x8 v; unsigned int u[4]; } out;
    out.u[0] = c0.u; out.u[1] = c1.u; out.u[2] = c2.u; out.u[3] = c3.u;
    return out.v;
}

// ---------------------------------------------------------------------------
// bf16 MFMA GEMM: C[m,n] = sum_k A[m,k] * Bw[n,k]  (both row-major, K contig)
// 128x128 block tile, BK=64, 256 threads = 4 waves, wave = 64x64 quadrant of
// 4x4 MFMA 16x16x32 tiles. fp32->bf16 conversion fused into LDS staging.
// MODE 0: plain store. MODE 1: in_proj split (xs_raw | silu->C1).
// MODE 2: dt (bias+softplus).
// ---------------------------------------------------------------------------
template <int MODE>
__global__ __launch_bounds__(256) void gemm_mfma(
    const float* __restrict__ A, const float* __restrict__ Bw,
    float* __restrict__ C0, float* __restrict__ C1,
    const float* __restrict__ bias, int M, int N, int K)
{
    constexpr int BK  = 64;
    constexpr int LDT = 72;   // row stride in bf16 elems (pad 8 -> 2-way only)
    __shared__ unsigned short As[128 * LDT];
    __shared__ unsigned short Bs[128 * LDT];

    const int tid  = threadIdx.x;
    const int lane = tid & 63;
    const int wave = tid >> 6;
    const int m0 = blockIdx.y * 128;
    const int n0 = blockIdx.x * 128;
    const int wm = (wave & 1) * 64;
    const int wn = (wave >> 1) * 64;
    const int col = lane & 15;   // MFMA m/n index within 16-tile
    const int kg  = lane >> 4;   // MFMA k-group (8 contiguous k each)

    f32x4 acc[4][4] = {};

    for (int kt = 0; kt < K; kt += BK) {
        // stage A and B tiles: 128 rows x 64 k, fp32 -> bf16
        #pragma unroll
        for (int it = 0; it < 4; ++it) {
            const int idx  = tid + it * 256;   // 0..1023
            const int row  = idx >> 3;
            const int half = idx & 7;          // 8 floats each
            const float4* pa = (const float4*)(A  + (size_t)(m0 + row) * K + kt + half * 8);
            const float4* pb = (const float4*)(Bw + (size_t)(n0 + row) * K + kt + half * 8);
            const float4 a0 = pa[0], a1 = pa[1];
            const float4 b0 = pb[0], b1 = pb[1];
            *(u16x8*)&As[row * LDT + half * 8] = cvt8_bf16(a0, a1);
            *(u16x8*)&Bs[row * LDT + half * 8] = cvt8_bf16(b0, b1);
        }
        __syncthreads();

        #pragma unroll
        for (int kk = 0; kk < 2; ++kk) {   // two 16x16x32 k-steps per BK=64
            bf16x8 af[4], bfr[4];
            #pragma unroll
            for (int i = 0; i < 4; ++i)
                af[i]  = *(const bf16x8*)&As[(wm + 16 * i + col) * LDT + kk * 32 + kg * 8];
            #pragma unroll
            for (int j = 0; j < 4; ++j)
                bfr[j] = *(const bf16x8*)&Bs[(wn + 16 * j + col) * LDT + kk * 32 + kg * 8];
            #pragma unroll
            for (int i = 0; i < 4; ++i)
                #pragma unroll
                for (int j = 0; j < 4; ++j)
                    acc[i][j] = __builtin_amdgcn_mfma_f32_16x16x32_bf16(
                        af[i], bfr[j], acc[i][j], 0, 0, 0);
        }
        __syncthreads();
    }

    // epilogue: C/D layout col=lane&15, row=(lane>>4)*4+reg
    #pragma unroll
    for (int i = 0; i < 4; ++i) {
        #pragma unroll
        for (int j = 0; j < 4; ++j) {
            const int n = n0 + wn + 16 * j + col;
            #pragma unroll
            for (int r = 0; r < 4; ++r) {
                const int m = m0 + wm + 16 * i + kg * 4 + r;
                float v = acc[i][j][r];
                if (MODE == 0) {
                    C0[(size_t)m * N + n] = v;
                } else if (MODE == 1) {
                    if (n < DINNER) C0[(size_t)m * DINNER + n] = v;
                    else            C1[(size_t)m * DINNER + (n - DINNER)] = silu_f(v);
                } else {
                    v += bias[n];
                    C0[(size_t)m * DINNER + n] = softplus_f(v);
                }
            }
        }
    }
}

// ---------------------------------------------------------------------------
// Causal depthwise conv (width 4) + bias + silu.
// ---------------------------------------------------------------------------
__global__ __launch_bounds__(256) void conv_silu_kernel(
    const float* __restrict__ xs_raw, const float* __restrict__ w,
    const float* __restrict__ bconv, float* __restrict__ xs)
{
    const size_t idx = (size_t)blockIdx.x * 256 + threadIdx.x;
    const int d = (int)(idx & (DINNER - 1));
    const int bt = (int)(idx >> 10);
    const int t = bt & (T_SEQ - 1);
    float acc = bconv[d];
    #pragma unroll
    for (int k = 0; k < 4; ++k) {
        const int tt = t + k - 3;
        if (tt >= 0)
            acc = fmaf(xs_raw[(size_t)(bt + k - 3) * DINNER + d], w[d * 4 + k], acc);
    }
    xs[idx] = silu_f(acc);
}

// ---------------------------------------------------------------------------
// B/C projections: one block per (b,t) row.
// ---------------------------------------------------------------------------
__global__ __launch_bounds__(256) void bc_proj_kernel(
    const float* __restrict__ xs, const float* __restrict__ bw,
    const float* __restrict__ cw, float* __restrict__ Bm, float* __restrict__ Cm)
{
    __shared__ float row[DINNER];
    const int bt = blockIdx.x;
    const int tid = threadIdx.x;
    const float* xr = xs + (size_t)bt * DINNER;
    for (int i = tid; i < DINNER; i += 256) row[i] = xr[i];
    __syncthreads();

    const int o = tid >> 3;
    const int part = tid & 7;
    const float* w = (o < NSTATE) ? (bw + (size_t)o * DINNER)
                                  : (cw + (size_t)(o - NSTATE) * DINNER);
    float s = 0.f;
    for (int k = part; k < DINNER; k += 8)
        s = fmaf(row[k], w[k], s);
    s += __shfl_xor(s, 1);
    s += __shfl_xor(s, 2);
    s += __shfl_xor(s, 4);
    if (part == 0) {
        if (o < NSTATE) Bm[(size_t)bt * NSTATE + o] = s;
        else            Cm[(size_t)bt * NSTATE + (o - NSTATE)] = s;
    }
}

// ---------------------------------------------------------------------------
// Chunked scan, phase 1: per (b, d, chunk) thread, 16 states in registers.
// ---------------------------------------------------------------------------
__global__ __launch_bounds__(256) void scan_phase1(
    const float* __restrict__ delta, const float* __restrict__ xs,
    const float* __restrict__ Bm, const float* __restrict__ A_log,
    float* __restrict__ Pbuf, float* __restrict__ Sbuf)
{
    const int tid = threadIdx.x;
    const int d = blockIdx.x * 256 + tid;
    const int c = blockIdx.y;
    const int b = blockIdx.z;

    float a[16], h[16], P[16];
    #pragma unroll
    for (int q = 0; q < 4; ++q)
        *(float4*)(a + 4 * q) = ((const float4*)(A_log + (size_t)d * NSTATE))[q];
    #pragma unroll
    for (int n = 0; n < 16; ++n) { a[n] = -__expf(a[n]); h[n] = 0.f; P[n] = 1.f; }

    const size_t base = (size_t)b * T_SEQ + (size_t)c * CLEN;
    for (int i = 0; i < CLEN; ++i) {
        const size_t bt = base + i;
        const float dlt = delta[bt * DINNER + d];
        const float xv  = xs[bt * DINNER + d];
        float Bn[16];
        #pragma unroll
        for (int q = 0; q < 4; ++q)
            *(float4*)(Bn + 4 * q) = ((const float4*)(Bm + bt * NSTATE))[q];
        const float tmp = dlt * xv;
        #pragma unroll
        for (int n = 0; n < 16; ++n) {
            const float dA = __expf(dlt * a[n]);
            P[n] *= dA;
            h[n] = fmaf(dA, h[n], tmp * Bn[n]);
        }
    }

    float* pp = Pbuf + ((((size_t)b * NCHUNK + c) * DINNER + d) * NSTATE);
    float* sp = Sbuf + ((((size_t)b * NCHUNK + c) * DINNER + d) * NSTATE);
    #pragma unroll
    for (int q = 0; q < 4; ++q) {
        ((float4*)pp)[q] = *(float4*)(P + 4 * q);
        ((float4*)sp)[q] = *(float4*)(h + 4 * q);
    }
}

// ---------------------------------------------------------------------------
// Phase 2: serial combine across chunks per (b,d,n).
// ---------------------------------------------------------------------------
__global__ __launch_bounds__(256) void scan_phase2(
    const float* __restrict__ Pbuf, const float* __restrict__ Sbuf,
    float* __restrict__ Hbuf)
{
    const size_t g = (size_t)blockIdx.x * 256 + threadIdx.x;
    const size_t b = g / (DINNER * NSTATE);
    const size_t r = g - b * (DINNER * NSTATE);
    float h = 0.f;
    #pragma unroll 4
    for (int c = 0; c < NCHUNK; ++c) {
        const size_t off = ((size_t)(b * NCHUNK + c)) * (DINNER * NSTATE) + r;
        Hbuf[off] = h;
        h = fmaf(Pbuf[off], h, Sbuf[off]);
    }
}

// ---------------------------------------------------------------------------
// Phase 3: replay chunk from entry state; fused y = (h*C + xs*D)*silu(res).
// ---------------------------------------------------------------------------
__global__ __launch_bounds__(256) void scan_phase3(
    const float* __restrict__ delta, const float* __restrict__ xs,
    const float* __restrict__ Bm, const float* __restrict__ Cm,
    const float* __restrict__ A_log, const float* __restrict__ Dp,
    const float* __restrict__ silures, const float* __restrict__ Hbuf,
    float* __restrict__ yfin)
{
    const int tid = threadIdx.x;
    const int d = blockIdx.x * 256 + tid;
    const int c = blockIdx.y;
    const int b = blockIdx.z;

    float a[16], h[16];
    #pragma unroll
    for (int q = 0; q < 4; ++q)
        *(float4*)(a + 4 * q) = ((const float4*)(A_log + (size_t)d * NSTATE))[q];
    #pragma unroll
    for (int n = 0; n < 16; ++n) a[n] = -__expf(a[n]);

    const float* hp = Hbuf + ((((size_t)b * NCHUNK + c) * DINNER + d) * NSTATE);
    #pragma unroll
    for (int q = 0; q < 4; ++q)
        *(float4*)(h + 4 * q) = ((const float4*)hp)[q];

    const float Dd = Dp[d];
    const size_t base = (size_t)b * T_SEQ + (size_t)c * CLEN;
    for (int i = 0; i < CLEN; ++i) {
        const size_t bt = base + i;
        const float dlt = delta[bt * DINNER + d];
        const float xv  = xs[bt * DINNER + d];
        const float sr  = silures[bt * DINNER + d];
        float Bn[16], Cn[16];
        #pragma unroll
        for (int q = 0; q < 4; ++q) {
            *(float4*)(Bn + 4 * q) = ((const float4*)(Bm + bt * NSTATE))[q];
            *(float4*)(Cn + 4 * q) = ((const float4*)(Cm + bt * NSTATE))[q];
        }
        const float tmp = dlt * xv;
        float p = 0.f;
        #pragma unroll
        for (int n = 0; n < 16; ++n) {
            const float dA = __expf(dlt * a[n]);
            h[n] = fmaf(dA, h[n], tmp * Bn[n]);
            p = fmaf(h[n], Cn[n], p);
        }
        const float y = fmaf(xv, Dd, p);
        yfin[bt * DINNER + d] = y * sr;
    }
}

// ---------------------------------------------------------------------------
extern "C" void kernel_launch(void* const* d_in, const int* in_sizes, int n_in,
                              void* d_out, int out_size, void* d_ws, size_t ws_size,
                              hipStream_t stream)
{
    const float* x          = (const float*)d_in[0];
    const float* in_proj_w  = (const float*)d_in[1];
    const float* conv_w     = (const float*)d_in[2];
    const float* conv_b     = (const float*)d_in[3];
    const float* b_proj_w   = (const float*)d_in[4];
    const float* c_proj_w   = (const float*)d_in[5];
    const float* dt_proj_w  = (const float*)d_in[6];
    const float* dt_proj_b  = (const float*)d_in[7];
    const float* A_log      = (const float*)d_in[8];
    const float* Dp         = (const float*)d_in[9];
    const float* out_proj_w = (const float*)d_in[10];
    float* out = (float*)d_out;

    const size_t BT = (size_t)BATCH * T_SEQ;   // 8192
    const size_t SZ = BT * DINNER;             // 8388608 floats (32 MB)
    const size_t PS = (size_t)BATCH * NCHUNK * DINNER * NSTATE; // 16 MB

    float* ws       = (float*)d_ws;
    float* xs_raw   = ws;                 // [BT, DINNER]; later P|S; later yfin
    float* xs       = ws + SZ;
    float* silures  = ws + 2 * SZ;
    float* delta    = ws + 3 * SZ;
    float* Bm       = ws + 4 * SZ;
    float* Cm       = Bm + BT * NSTATE;
    float* Hbuf     = Cm + BT * NSTATE;
    float* Pbuf     = xs_raw;
    float* Sbuf     = xs_raw + PS;
    float* yfin     = xs_raw;

    // 1. in_proj (bf16 MFMA)
    gemm_mfma<1><<<dim3(2 * DINNER / 128, BT / 128), 256, 0, stream>>>(
        x, in_proj_w, xs_raw, silures, nullptr, (int)BT, 2 * DINNER, DMODEL);

    // 2. conv + bias + silu
    conv_silu_kernel<<<dim3((unsigned)(SZ / 256)), 256, 0, stream>>>(xs_raw, conv_w, conv_b, xs);

    // 3. delta = softplus(xs @ dt_proj_w^T + b)  (bf16 MFMA)
    gemm_mfma<2><<<dim3(DINNER / 128, BT / 128), 256, 0, stream>>>(
        xs, dt_proj_w, delta, nullptr, dt_proj_b, (int)BT, DINNER, DINNER);

    // 4. B/C projections
    bc_proj_kernel<<<dim3((unsigned)BT), 256, 0, stream>>>(xs, b_proj_w, c_proj_w, Bm, Cm);

    // 5. chunked selective scan
    scan_phase1<<<dim3(DINNER / 256, NCHUNK, BATCH), 256, 0, stream>>>(
        delta, xs, Bm, A_log, Pbuf, Sbuf);
    scan_phase2<<<dim3((unsigned)((BATCH * DINNER * NSTATE) / 256)), 256, 0, stream>>>(
        Pbuf, Sbuf, Hbuf);
    scan_phase3<<<dim3(DINNER / 256, NCHUNK, BATCH), 256, 0, stream>>>(
        delta, xs, Bm, Cm, A_log, Dp, silures, Hbuf, yfin);

    // 6. out_proj (bf16 MFMA)
    gemm_mfma<0><<<dim3(DMODEL / 128, BT / 128), 256, 0, stream>>>(
        yfin, out_proj_w, out, nullptr, nullptr, (int)BT, DMODEL, DINNER);
}

// Round 4
// 369.845 us; speedup vs baseline: 3.9110x; 1.2136x over previous
//
#include <hip/hip_runtime.h>
#include <hip/hip_bf16.h>
#include <cstddef>

#define T_SEQ 2048
#define BATCH 4
#define DMODEL 512
#define DINNER 1024
#define NSTATE 16
#define NCHUNK 64
#define CLEN   32   // T_SEQ / NCHUNK

typedef __attribute__((ext_vector_type(8))) short bf16x8;   // MFMA A/B operand
typedef __attribute__((ext_vector_type(4))) float f32x4;    // MFMA C/D
typedef __attribute__((ext_vector_type(8))) unsigned short u16x8;

__device__ __forceinline__ float silu_f(float v) { return v / (1.f + __expf(-v)); }
__device__ __forceinline__ float softplus_f(float v) { return v > 20.f ? v : log1pf(__expf(v)); }

__device__ __forceinline__ u16x8 cvt8_bf16(const float4 a, const float4 b) {
    union { __hip_bfloat162 h; unsigned int u; } c0, c1, c2, c3;
    c0.h = __float22bfloat162_rn(make_float2(a.x, a.y));
    c1.h = __float22bfloat162_rn(make_float2(a.z, a.w));
    c2.h = __float22bfloat162_rn(make_float2(b.x, b.y));
    c3.h = __float22bfloat162_rn(make_float2(b.z, b.w));
    union { u16x8 v; unsigned int u[4]; } out;
    out.u[0] = c0.u; out.u[1] = c1.u; out.u[2] = c2.u; out.u[3] = c3.u;
    return out.v;
}

__device__ __forceinline__ float bf2f(unsigned short u) {
    union { float f; unsigned int i; } c; c.i = ((unsigned int)u) << 16; return c.f;
}
__device__ __forceinline__ unsigned short f2bf(float f) {
    union { __hip_bfloat16 h; unsigned short u; } c; c.h = __float2bfloat16(f); return c.u;
}

// ---------------------------------------------------------------------------
// One-shot fp32 -> bf16 conversion of x + all GEMM weights (dt|b|c concat).
// blockIdx.y selects segment; each thread converts one 8-elem chunk.
// ---------------------------------------------------------------------------
__global__ __launch_bounds__(256) void cvt_all(
    const float* __restrict__ x, const float* __restrict__ w_in,
    const float* __restrict__ w_dt, const float* __restrict__ w_b,
    const float* __restrict__ w_c, const float* __restrict__ w_out,
    unsigned short* __restrict__ x_bf, unsigned short* __restrict__ w_in_bf,
    unsigned short* __restrict__ wcat, unsigned short* __restrict__ w_out_bf)
{
    const int seg = blockIdx.y;
    const size_t i8 = (size_t)blockIdx.x * 256 + threadIdx.x; // chunk index
    const float* src; unsigned short* dst; size_t n;
    switch (seg) {
        case 0: src = x;     dst = x_bf;                n = (size_t)BATCH * T_SEQ * DMODEL; break;
        case 1: src = w_in;  dst = w_in_bf;             n = (size_t)2 * DINNER * DMODEL;    break;
        case 2: src = w_dt;  dst = wcat;                n = (size_t)DINNER * DINNER;        break;
        case 3: src = w_b;   dst = wcat + (size_t)1024 * DINNER; n = (size_t)NSTATE * DINNER; break;
        case 4: src = w_c;   dst = wcat + (size_t)1040 * DINNER; n = (size_t)NSTATE * DINNER; break;
        default: src = w_out; dst = w_out_bf;           n = (size_t)DMODEL * DINNER;        break;
    }
    if (i8 * 8 >= n) return;
    const float4 a = ((const float4*)src)[i8 * 2];
    const float4 b = ((const float4*)src)[i8 * 2 + 1];
    *(u16x8*)(dst + i8 * 8) = cvt8_bf16(a, b);
}

// ---------------------------------------------------------------------------
// bf16 MFMA GEMM (m97-style): C[m,n] = sum_k A[m,k]*Bw[n,k], A/B bf16 row-major.
// 128x128 tile, BK=64, 256 thr = 4 waves (64x64 quadrant, 4x4 MFMA 16x16x32).
// Staging via global_load_lds 16B; LDS k-chunks XOR-swizzled by row&7 so the
// fragment ds_read_b128s are 2-way-only on banks (free) while keeping the
// wave-uniform-base + lane*16 contiguity global_load_lds requires.
// MODE 0: C0[m*N+n] (out_proj).
// MODE 1: in_proj: n<1024 -> C0 fp32 (xs_raw); else C1h = bf16(silu).
// MODE 2: dt|b|c: n<1024 -> C0=softplus(v+bias[n]); n<1040 -> C1f (Bm);
//         n<1056 -> C2f (Cm); else drop (wcat pad rows are poison, discarded).
// ---------------------------------------------------------------------------
template <int MODE>
__global__ __launch_bounds__(256) void gemm_bf16(
    const unsigned short* __restrict__ A, const unsigned short* __restrict__ Bw,
    float* __restrict__ C0, float* __restrict__ C1f, float* __restrict__ C2f,
    unsigned short* __restrict__ C1h, const float* __restrict__ bias,
    int M, int N, int K)
{
    __shared__ unsigned short As[128 * 64];
    __shared__ unsigned short Bs[128 * 64];

    const int tid  = threadIdx.x;
    const int lane = tid & 63;
    const int wave = tid >> 6;
    const int m0 = blockIdx.y * 128;
    const int n0 = blockIdx.x * 128;
    const int wm = (wave & 1) * 64;
    const int wn = (wave >> 1) * 64;
    const int col = lane & 15;
    const int kg  = lane >> 4;     // 0..3
    const int r8  = lane >> 3;     // 0..7 (staging row within 8-row group)
    const int c8  = lane & 7;      // 0..7 (staging k-chunk)

    f32x4 acc[4][4] = {};

    for (int kt = 0; kt < K; kt += 64) {
        #pragma unroll
        for (int it = 0; it < 4; ++it) {
            const int rowb = it * 32 + wave * 8;       // wave-uniform
            const int kc   = c8 ^ r8;                  // swizzled global k-chunk
            const unsigned short* ga = A  + (size_t)(m0 + rowb + r8) * K + kt + kc * 8;
            const unsigned short* gb = Bw + (size_t)(n0 + rowb + r8) * K + kt + kc * 8;
            __builtin_amdgcn_global_load_lds(
                (const __attribute__((address_space(1))) void*)ga,
                (__attribute__((address_space(3))) void*)(As + rowb * 64), 16, 0, 0);
            __builtin_amdgcn_global_load_lds(
                (const __attribute__((address_space(1))) void*)gb,
                (__attribute__((address_space(3))) void*)(Bs + rowb * 64), 16, 0, 0);
        }
        __syncthreads();

        #pragma unroll
        for (int kk = 0; kk < 2; ++kk) {
            bf16x8 af[4], bfr[4];
            #pragma unroll
            for (int i = 0; i < 4; ++i) {
                const int row = wm + 16 * i + col;
                const int c = ((kk * 4 + kg) ^ (row & 7)) * 8;
                af[i] = *(const bf16x8*)&As[row * 64 + c];
            }
            #pragma unroll
            for (int j = 0; j < 4; ++j) {
                const int row = wn + 16 * j + col;
                const int c = ((kk * 4 + kg) ^ (row & 7)) * 8;
                bfr[j] = *(const bf16x8*)&Bs[row * 64 + c];
            }
            #pragma unroll
            for (int i = 0; i < 4; ++i)
                #pragma unroll
                for (int j = 0; j < 4; ++j)
                    acc[i][j] = __builtin_amdgcn_mfma_f32_16x16x32_bf16(
                        af[i], bfr[j], acc[i][j], 0, 0, 0);
        }
        __syncthreads();
    }

    // epilogue: C/D layout col=lane&15, row=(lane>>4)*4+reg
    #pragma unroll
    for (int i = 0; i < 4; ++i) {
        #pragma unroll
        for (int j = 0; j < 4; ++j) {
            const int n = n0 + wn + 16 * j + col;
            #pragma unroll
            for (int r = 0; r < 4; ++r) {
                const int m = m0 + wm + 16 * i + kg * 4 + r;
                float v = acc[i][j][r];
                if (MODE == 0) {
                    C0[(size_t)m * N + n] = v;
                } else if (MODE == 1) {
                    if (n < DINNER) C0[(size_t)m * DINNER + n] = v;
                    else            C1h[(size_t)m * DINNER + (n - DINNER)] = f2bf(silu_f(v));
                } else {
                    if (n < DINNER) {
                        C0[(size_t)m * DINNER + n] = softplus_f(v + bias[n]);
                    } else if (n < DINNER + NSTATE) {
                        C1f[(size_t)m * NSTATE + (n - DINNER)] = v;
                    } else if (n < DINNER + 2 * NSTATE) {
                        C2f[(size_t)m * NSTATE + (n - DINNER - NSTATE)] = v;
                    }
                }
            }
        }
    }
}

// ---------------------------------------------------------------------------
// Causal depthwise conv (width 4) + bias + silu -> bf16.
// ---------------------------------------------------------------------------
__global__ __launch_bounds__(256) void conv_silu_kernel(
    const float* __restrict__ xs_raw, const float* __restrict__ w,
    const float* __restrict__ bconv, unsigned short* __restrict__ xs_bf)
{
    const size_t idx = (size_t)blockIdx.x * 256 + threadIdx.x;
    const int d = (int)(idx & (DINNER - 1));
    const int bt = (int)(idx >> 10);
    const int t = bt & (T_SEQ - 1);
    float acc = bconv[d];
    #pragma unroll
    for (int k = 0; k < 4; ++k) {
        const int tt = t + k - 3;
        if (tt >= 0)
            acc = fmaf(xs_raw[(size_t)(bt + k - 3) * DINNER + d], w[d * 4 + k], acc);
    }
    xs_bf[idx] = f2bf(silu_f(acc));
}

// ---------------------------------------------------------------------------
// Chunked scan, phase 1: per (b, d, chunk) thread, 16 states in registers.
// ---------------------------------------------------------------------------
__global__ __launch_bounds__(256) void scan_phase1(
    const float* __restrict__ delta, const unsigned short* __restrict__ xs_bf,
    const float* __restrict__ Bm, const float* __restrict__ A_log,
    float* __restrict__ Pbuf, float* __restrict__ Sbuf)
{
    const int tid = threadIdx.x;
    const int d = blockIdx.x * 256 + tid;
    const int c = blockIdx.y;
    const int b = blockIdx.z;

    float a[16], h[16], P[16];
    #pragma unroll
    for (int q = 0; q < 4; ++q)
        *(float4*)(a + 4 * q) = ((const float4*)(A_log + (size_t)d * NSTATE))[q];
    #pragma unroll
    for (int n = 0; n < 16; ++n) { a[n] = -__expf(a[n]); h[n] = 0.f; P[n] = 1.f; }

    const size_t base = (size_t)b * T_SEQ + (size_t)c * CLEN;
    for (int i = 0; i < CLEN; ++i) {
        const size_t bt = base + i;
        const float dlt = delta[bt * DINNER + d];
        const float xv  = bf2f(xs_bf[bt * DINNER + d]);
        float Bn[16];
        #pragma unroll
        for (int q = 0; q < 4; ++q)
            *(float4*)(Bn + 4 * q) = ((const float4*)(Bm + bt * NSTATE))[q];
        const float tmp = dlt * xv;
        #pragma unroll
        for (int n = 0; n < 16; ++n) {
            const float dA = __expf(dlt * a[n]);
            P[n] *= dA;
            h[n] = fmaf(dA, h[n], tmp * Bn[n]);
        }
    }

    float* pp = Pbuf + ((((size_t)b * NCHUNK + c) * DINNER + d) * NSTATE);
    float* sp = Sbuf + ((((size_t)b * NCHUNK + c) * DINNER + d) * NSTATE);
    #pragma unroll
    for (int q = 0; q < 4; ++q) {
        ((float4*)pp)[q] = *(float4*)(P + 4 * q);
        ((float4*)sp)[q] = *(float4*)(h + 4 * q);
    }
}

// ---------------------------------------------------------------------------
// Phase 2: serial combine across chunks per (b,d,n).
// ---------------------------------------------------------------------------
__global__ __launch_bounds__(256) void scan_phase2(
    const float* __restrict__ Pbuf, const float* __restrict__ Sbuf,
    float* __restrict__ Hbuf)
{
    const size_t g = (size_t)blockIdx.x * 256 + threadIdx.x;
    const size_t b = g / (DINNER * NSTATE);
    const size_t r = g - b * (DINNER * NSTATE);
    float h = 0.f;
    #pragma unroll 4
    for (int c = 0; c < NCHUNK; ++c) {
        const size_t off = ((size_t)(b * NCHUNK + c)) * (DINNER * NSTATE) + r;
        Hbuf[off] = h;
        h = fmaf(Pbuf[off], h, Sbuf[off]);
    }
}

// ---------------------------------------------------------------------------
// Phase 3: replay chunk from entry state; y = (h*C + xs*D)*silu(res) -> bf16.
// ---------------------------------------------------------------------------
__global__ __launch_bounds__(256) void scan_phase3(
    const float* __restrict__ delta, const unsigned short* __restrict__ xs_bf,
    const float* __restrict__ Bm, const float* __restrict__ Cm,
    const float* __restrict__ A_log, const float* __restrict__ Dp,
    const unsigned short* __restrict__ sr_bf, const float* __restrict__ Hbuf,
    unsigned short* __restrict__ yfin_bf)
{
    const int tid = threadIdx.x;
    const int d = blockIdx.x * 256 + tid;
    const int c = blockIdx.y;
    const int b = blockIdx.z;

    float a[16], h[16];
    #pragma unroll
    for (int q = 0; q < 4; ++q)
        *(float4*)(a + 4 * q) = ((const float4*)(A_log + (size_t)d * NSTATE))[q];
    #pragma unroll
    for (int n = 0; n < 16; ++n) a[n] = -__expf(a[n]);

    const float* hp = Hbuf + ((((size_t)b * NCHUNK + c) * DINNER + d) * NSTATE);
    #pragma unroll
    for (int q = 0; q < 4; ++q)
        *(float4*)(h + 4 * q) = ((const float4*)hp)[q];

    const float Dd = Dp[d];
    const size_t base = (size_t)b * T_SEQ + (size_t)c * CLEN;
    for (int i = 0; i < CLEN; ++i) {
        const size_t bt = base + i;
        const float dlt = delta[bt * DINNER + d];
        const float xv  = bf2f(xs_bf[bt * DINNER + d]);
        const float sr  = bf2f(sr_bf[bt * DINNER + d]);
        float Bn[16], Cn[16];
        #pragma unroll
        for (int q = 0; q < 4; ++q) {
            *(float4*)(Bn + 4 * q) = ((const float4*)(Bm + bt * NSTATE))[q];
            *(float4*)(Cn + 4 * q) = ((const float4*)(Cm + bt * NSTATE))[q];
        }
        const float tmp = dlt * xv;
        float p = 0.f;
        #pragma unroll
        for (int n = 0; n < 16; ++n) {
            const float dA = __expf(dlt * a[n]);
            h[n] = fmaf(dA, h[n], tmp * Bn[n]);
            p = fmaf(h[n], Cn[n], p);
        }
        const float y = fmaf(xv, Dd, p);
        yfin_bf[bt * DINNER + d] = f2bf(y * sr);
    }
}

// ---------------------------------------------------------------------------
extern "C" void kernel_launch(void* const* d_in, const int* in_sizes, int n_in,
                              void* d_out, int out_size, void* d_ws, size_t ws_size,
                              hipStream_t stream)
{
    const float* x          = (const float*)d_in[0];
    const float* in_proj_w  = (const float*)d_in[1];
    const float* conv_w     = (const float*)d_in[2];
    const float* conv_b     = (const float*)d_in[3];
    const float* b_proj_w   = (const float*)d_in[4];
    const float* c_proj_w   = (const float*)d_in[5];
    const float* dt_proj_w  = (const float*)d_in[6];
    const float* dt_proj_b  = (const float*)d_in[7];
    const float* A_log      = (const float*)d_in[8];
    const float* Dp         = (const float*)d_in[9];
    const float* out_proj_w = (const float*)d_in[10];
    float* out = (float*)d_out;

    const size_t BT = (size_t)BATCH * T_SEQ;   // 8192
    const size_t SZ = BT * DINNER;             // 8,388,608
    const size_t PS = (size_t)BATCH * NCHUNK * DINNER * NSTATE; // 4,194,304

    float* ws = (float*)d_ws;
    float* xs_raw = ws;                       // [SZ] f32; later P|S; later yfin_bf
    float* delta  = ws + SZ;                  // [SZ] f32
    float* Bm     = ws + 2 * SZ;              // [BT*16] f32
    float* Cm     = Bm + BT * NSTATE;
    float* Hbuf   = Cm + BT * NSTATE;         // [PS] f32
    unsigned short* xs_bf   = (unsigned short*)(Hbuf + PS);        // [SZ] bf16
    unsigned short* sr_bf   = xs_bf + SZ;                          // [SZ] bf16
    unsigned short* x_bf    = sr_bf + SZ;                          // [BT*512]
    unsigned short* w_in_bf = x_bf + BT * DMODEL;                  // [2048*512]
    unsigned short* wcat    = w_in_bf + (size_t)2 * DINNER * DMODEL; // [1152*1024]
    unsigned short* w_out_bf= wcat + (size_t)1152 * DINNER;        // [512*1024]
    float* Pbuf = xs_raw;
    float* Sbuf = xs_raw + PS;
    unsigned short* yfin_bf = (unsigned short*)xs_raw;

    // 0. one-shot bf16 conversion (x + all weights; dt|b|c concatenated)
    cvt_all<<<dim3(2048, 6), 256, 0, stream>>>(
        x, in_proj_w, dt_proj_w, b_proj_w, c_proj_w, out_proj_w,
        x_bf, w_in_bf, wcat, w_out_bf);

    // 1. in_proj: xs_raw f32 | sr_bf = bf16(silu(res))
    gemm_bf16<1><<<dim3(2 * DINNER / 128, BT / 128), 256, 0, stream>>>(
        x_bf, w_in_bf, xs_raw, nullptr, nullptr, sr_bf, nullptr,
        (int)BT, 2 * DINNER, DMODEL);

    // 2. conv + bias + silu -> xs_bf
    conv_silu_kernel<<<dim3((unsigned)(SZ / 256)), 256, 0, stream>>>(
        xs_raw, conv_w, conv_b, xs_bf);

    // 3. combined dt|B|C GEMM (N = 1152 logical, 9 tiles)
    gemm_bf16<2><<<dim3(9, BT / 128), 256, 0, stream>>>(
        xs_bf, wcat, delta, Bm, Cm, nullptr, dt_proj_b,
        (int)BT, 1152, DINNER);

    // 4. chunked selective scan
    scan_phase1<<<dim3(DINNER / 256, NCHUNK, BATCH), 256, 0, stream>>>(
        delta, xs_bf, Bm, A_log, Pbuf, Sbuf);
    scan_phase2<<<dim3((unsigned)((BATCH * DINNER * NSTATE) / 256)), 256, 0, stream>>>(
        Pbuf, Sbuf, Hbuf);
    scan_phase3<<<dim3(DINNER / 256, NCHUNK, BATCH), 256, 0, stream>>>(
        delta, xs_bf, Bm, Cm, A_log, Dp, sr_bf, Hbuf, yfin_bf);

    // 5. out_proj
    gemm_bf16<0><<<dim3(DMODEL / 128, BT / 128), 256, 0, stream>>>(
        yfin_bf, w_out_bf, out, nullptr, nullptr, nullptr, nullptr,
        (int)BT, DMODEL, DINNER);
}